// Round 8
// baseline (188.442 us; speedup 1.0000x reference)
//
#include <hip/hip_runtime.h>

// NumericalBiasModule: out[e] = b2 + W2 · relu(W1 · rel(x[src], x[dst]) + b1)
// rel = [ratio | log_ratio | abs_diff | rel_diff], 128 features.
//
// Round-25: r0 champion kernel (16-edge mfma_16x16x32 tiles, depth-2 gather
// pipeline, LDS just-in-time weights, 65.9us) + XCD-PINNED 8-bucket sort.
// Wall analysis: ~20.7K cyc/tile/wave vs ~700 issue cyc => ~75% gather-stall;
// depth-2 MLP neutral 3x => MSHR/outstanding-miss limited, so only LOWER
// LATENCY per access helps. r22 (256 buckets, unpinned) failed because
// consecutive tiles round-robin across XCDs -> every private L2 refetches the
// same window. Fix: bucket = src*8/N, block group g = blockIdx&7 (XCD g via
// round-robin dispatch) owns bucket g's tiles -> per-XCD src slice 1.6MB
// stays L2-resident; ~10 src touches/node -> ~9 L2 hits. Sort made cheap
// (r22's cost was the serial 256-bucket scan, ~60us): 8 buckets, per-block
// hist, 8-thread scan, LDS-cursor scatter (~10us total). Dispatch overhead
// measured ~1-2us (r23 vs r0) -- runtimes are what counts.
//
// MFMA tile (validated r4-r16): 16 edges/wave, mfma_f32_16x16x32_bf16.
// lane = (m=lane&15 edge, q=lane>>4 k-chunk); A-frag[j] = feat[m][q*8+j];
// C/D: col=lane&15 (hid), row=q*4+reg (edge).
// Packed node record (validated r16): per 8-dim chunk 32B = xh bf16[8] |
// xl8 u8[8] mantissa ext | lu8 u8[8] log-quant; 128B/node (precision-forced).
// Weights stay LDS just-in-time (r24 falsified register-resident: compiler
// scratch-spills 20 bf16x8 regardless of VGPR cap).

#define DD    32
#define HID   64
#define RELF  128
#define EPSF  1e-8f
#define LXLO  -18.420681f          // log(1e-8)
#define LXSC  13.843137f           // 255 / 18.420681
#define LXIV  0.07223796f          // 18.420681 / 255
#define MSC   3.0517578125e-05f    // 2^-15

#define NBUK  8                    // one bucket per XCD
#define SB_EB 4096                 // edges per sort block

typedef short  bf16x8 __attribute__((ext_vector_type(8)));
typedef float  f32x4  __attribute__((ext_vector_type(4)));

union U8 { unsigned u[4]; bf16x8 v; uint4 q4; };
union Q  { uint4 v; unsigned u[4]; float f[4]; };

static __device__ __forceinline__ unsigned pk_tr(float lo, float hi) {
    return __builtin_amdgcn_perm(__builtin_bit_cast(unsigned, hi),
                                 __builtin_bit_cast(unsigned, lo), 0x07060302u);
}
static __device__ __forceinline__ unsigned rne_bits(float f) {
    unsigned u = __builtin_bit_cast(unsigned, f);
    return u + 0x7fffu + ((u >> 16) & 1u);
}
static __device__ __forceinline__ unsigned pk_rne(float lo, float hi) {
    return __builtin_amdgcn_perm(rne_bits(hi), rne_bits(lo), 0x07060302u);
}
static __device__ __forceinline__ float hi_f32(float f) {
    return __builtin_bit_cast(float, __builtin_bit_cast(unsigned, f) & 0xffff0000u);
}
static __device__ __forceinline__ float ubyte(unsigned w, int b) {
    return (float)((w >> (8 * b)) & 0xffu);   // folds to v_cvt_f32_ubyteN
}
static __device__ __forceinline__ unsigned q8(float v) {
    int u = (int)(v + 0.5f);
    return (unsigned)(u > 255 ? 255 : (u < 0 ? 0 : u));
}
// pp += row_ror<N>(pp): within-16-lane rotate-add on the VALU pipe (DPP)
template <int CTRL>
static __device__ __forceinline__ float dpp_ror_add(float pp) {
    int s = __builtin_bit_cast(int, pp);
    int t = __builtin_amdgcn_update_dpp(0, s, CTRL, 0xf, 0xf, true);
    return pp + __builtin_bit_cast(float, t);
}

// ---- prep: one thread per (node, q) 8-dim chunk ----
__global__ __launch_bounds__(256)
void prep_pack(const float* __restrict__ x, uint4* __restrict__ rec, int nchunk)
{
    int i = blockIdx.x * blockDim.x + threadIdx.x;   // chunk = node*4 + q
    if (i >= nchunk) return;
    const float4* xp = (const float4*)(x + (size_t)i * 8);
    float4 v0 = xp[0], v1 = xp[1];
    float xv[8] = {v0.x, v0.y, v0.z, v0.w, v1.x, v1.y, v1.z, v1.w};

    unsigned xh[4];
    #pragma unroll
    for (int p = 0; p < 4; ++p) xh[p] = pk_tr(xv[2*p], xv[2*p+1]);

    unsigned xl[2] = {0u, 0u}, lu[2] = {0u, 0u};
    #pragma unroll
    for (int e = 0; e < 8; ++e) {
        float a  = xv[e];
        float ah = hi_f32(a);
        float f  = 0.f;
        if (ah > 0.f)
            f = (a * __builtin_amdgcn_rcpf(ah) - 1.f) * 32768.f;   // 2^15
        xl[e >> 2] |= q8(f) << (8 * (e & 3));
        float lxe = __logf(a + EPSF);
        lu[e >> 2] |= q8((lxe - LXLO) * LXSC) << (8 * (e & 3));
    }

    uint4 r0; r0.x = xh[0]; r0.y = xh[1]; r0.z = xh[2]; r0.w = xh[3];
    uint4 r1; r1.x = xl[0]; r1.y = xl[1]; r1.z = lu[0]; r1.w = lu[1];
    rec[2 * i]     = r0;
    rec[2 * i + 1] = r1;
}

// ---- sort K1: per-block 8-bucket histogram ----
__global__ __launch_bounds__(256)
void hist8(const int* __restrict__ ei, unsigned* __restrict__ H, int E, unsigned M)
{
    __shared__ unsigned lh[NBUK];
    const int tid = threadIdx.x, blk = blockIdx.x;
    if (tid < NBUK) lh[tid] = 0u;
    __syncthreads();
    const int base = blk * SB_EB;
    const int end  = (base + SB_EB < E) ? base + SB_EB : E;
    for (int e = base + tid; e < end; e += 256)
        atomicAdd(&lh[__umulhi((unsigned)ei[e], M)], 1u);
    __syncthreads();
    if (tid < NBUK) H[blk * NBUK + tid] = lh[tid];
}

// ---- sort K2: bucket bases + per-(block,bucket) starts (1 block, cheap) ----
__global__ __launch_bounds__(64)
void scan8(const unsigned* __restrict__ H, unsigned* __restrict__ Bk,
           unsigned* __restrict__ ebase, int nblk)
{
    __shared__ unsigned colsum[NBUK], basebuf[NBUK + 1];
    const int b = threadIdx.x;
    if (b < NBUK) {
        unsigned s = 0;
        for (int k = 0; k < nblk; ++k) s += H[k * NBUK + b];
        colsum[b] = s;
    }
    __syncthreads();
    if (b == 0) {
        unsigned run = 0;
        for (int i = 0; i < NBUK; ++i) { basebuf[i] = run; run += colsum[i]; }
        basebuf[NBUK] = run;
    }
    __syncthreads();
    if (b <= NBUK) ebase[b] = basebuf[b];
    if (b < NBUK) {
        unsigned run = basebuf[b];
        for (int k = 0; k < nblk; ++k) {
            Bk[k * NBUK + b] = run;
            run += H[k * NBUK + b];
        }
    }
}

// ---- sort K3: scatter edges to bucket-sorted arrays (LDS cursors) ----
__global__ __launch_bounds__(256)
void scatter8(const int* __restrict__ ei, const unsigned* __restrict__ Bk,
              int* __restrict__ ssrc, int* __restrict__ sdst,
              int* __restrict__ sidx, int E, unsigned M)
{
    __shared__ unsigned cur[NBUK];
    const int tid = threadIdx.x, blk = blockIdx.x;
    if (tid < NBUK) cur[tid] = Bk[blk * NBUK + tid];
    __syncthreads();
    const int base = blk * SB_EB;
    const int end  = (base + SB_EB < E) ? base + SB_EB : E;
    for (int e = base + tid; e < end; e += 256) {
        int s = ei[e], d = ei[E + e];
        unsigned pos = atomicAdd(&cur[__umulhi((unsigned)s, M)], 1u);
        ssrc[pos] = s; sdst[pos] = d; sidx[pos] = e;
    }
}

// PACK=1: packed records. SORTED=1: bucket-g tiles on XCD g, store via pidx.
template <int PACK, int SORTED>
__global__ __launch_bounds__(256, 4)
void edge_bias_mfma(const float* __restrict__ x,
                    const int*   __restrict__ psrc,   // [E]
                    const int*   __restrict__ pdst,   // [E]
                    const int*   __restrict__ pidx,   // [E] orig edge ids
                    const unsigned* __restrict__ ebase, // [9] bucket bases
                    const float* __restrict__ W1,     // [64, 128]
                    const float* __restrict__ b1,
                    const float* __restrict__ W2,
                    const float* __restrict__ b2,
                    const uint4* __restrict__ rec,    // [N, 8] packed
                    float* __restrict__ out,
                    int E)
{
    const int lane = threadIdx.x & 63;
    const int wv   = threadIdx.x >> 6;
    const int c = lane & 15;      // edge-in-tile (A) / hid-col (C)
    const int q = lane >> 4;      // k-chunk (A,B) / row-quad (C)

    // ---- LDS weight image: 5 sets x 4 nt = 20 frags x 1KB (r11/r12) ----
    __shared__ uint4 sW[20 * 64];
    for (int s = wv; s < 5; s += 4) {
        #pragma unroll
        for (int nt = 0; nt < 4; ++nt) {
            const float* wr = W1 + (nt * 16 + c) * RELF + q * 8;
            U8 t;
            if (s == 0) {
                #pragma unroll
                for (int p = 0; p < 4; ++p)
                    t.u[p] = pk_tr(wr[2*p], wr[2*p+1]);
            } else if (s == 1) {
                #pragma unroll
                for (int p = 0; p < 4; ++p) {
                    float w0 = wr[2*p], w1 = wr[2*p+1];
                    t.u[p] = pk_rne(w0 - hi_f32(w0), w1 - hi_f32(w1));
                }
            } else {
                const int base = (s == 2) ? 32 : (s == 3) ? 64 : 96;
                #pragma unroll
                for (int p = 0; p < 4; ++p)
                    t.u[p] = pk_rne(wr[base + 2*p], wr[base + 2*p + 1]);
            }
            sW[(s * 4 + nt) * 64 + lane] = t.q4;
        }
    }
    __syncthreads();

    float b1v[4], w2v[4];
    #pragma unroll
    for (int nt = 0; nt < 4; ++nt) {
        b1v[nt] = b1[nt * 16 + c];
        w2v[nt] = W2[nt * 16 + c];
    }
    const float b2s = b2[0];

    // ---- tile range: bucket g pinned to XCD g via blockIdx%8 ----
    const int ntiles = (E + 15) >> 4;
    int t, t1, tstep;
    if constexpr (SORTED) {
        const int g  = blockIdx.x & 7;
        const int bi = blockIdx.x >> 3;
        const int eb0 = (int)ebase[g], eb1 = (int)ebase[g + 1];
        const int t0 = (eb0 + 15) >> 4;        // ceil boundaries: disjoint,
        t1 = (eb1 + 15) >> 4;                  // union covers all tiles
        tstep = (gridDim.x >> 3) * (blockDim.x >> 6);
        t = t0 + bi * (blockDim.x >> 6) + wv;
    } else {
        const int wave = (blockIdx.x * blockDim.x + threadIdx.x) >> 6;
        tstep = (gridDim.x * blockDim.x) >> 6;
        t = wave; t1 = ntiles;
    }
    if (t >= t1) return;

    auto ldidx = [&](int tt_, int& s, int& d) {
        if (tt_ >= t1) tt_ = t;
        int em = (tt_ << 4) + c; if (em > E - 1) em = E - 1;
        s = psrc[em]; d = pdst[em];
    };
    auto gather = [&](int s, int d, Q& hi_, Q& mi_, Q& hj_, Q& mj_) {
        if constexpr (PACK) {
            const uint4* pi = rec + (size_t)s * 8 + q * 2;
            const uint4* pj = rec + (size_t)d * 8 + q * 2;
            hi_.v = pi[0]; mi_.v = pi[1];
            hj_.v = pj[0]; mj_.v = pj[1];
        } else {
            const uint4* pi = (const uint4*)(x + (size_t)s * DD + q * 8);
            const uint4* pj = (const uint4*)(x + (size_t)d * DD + q * 8);
            hi_.v = pi[0]; mi_.v = pi[1];
            hj_.v = pj[0]; mj_.v = pj[1];
        }
    };
    // decode one packed side -> 8 fp32 x + bf16 log A-frag
    auto decode = [&](const Q& h, const Q& m, float* xv, bf16x8& lfrag) {
        #pragma unroll
        for (int p = 0; p < 4; ++p) {
            float lo = __builtin_bit_cast(float, h.u[p] << 16);
            float hi = __builtin_bit_cast(float, h.u[p] & 0xffff0000u);
            unsigned xb = (p < 2) ? m.u[0] : m.u[1];
            float m0 = ubyte(xb, (2 * p) & 3);
            float m1 = ubyte(xb, (2 * p + 1) & 3);
            xv[2 * p]     = fmaf(lo * MSC, m0, lo);
            xv[2 * p + 1] = fmaf(hi * MSC, m1, hi);
        }
        U8 L;
        #pragma unroll
        for (int p = 0; p < 4; ++p) {
            unsigned lb = (p < 2) ? m.u[2] : m.u[3];
            float l0 = fmaf(ubyte(lb, (2 * p) & 3),     LXIV, LXLO);
            float l1 = fmaf(ubyte(lb, (2 * p + 1) & 3), LXIV, LXLO);
            L.u[p] = pk_tr(l0, l1);   // truncate: lx already quantized at 0.036
        }
        lfrag = L.v;
    };

    auto compute = [&](int tc, const Q& hI, const Q& mI, const Q& hJ, const Q& mJ) {
        float xiv[8], xjv[8];
        bf16x8 aLi, aLj;
        if constexpr (PACK) {
            decode(hI, mI, xiv, aLi);
            decode(hJ, mJ, xjv, aLj);
        } else {
            #pragma unroll
            for (int p = 0; p < 4; ++p) { xiv[p] = hI.f[p]; xiv[4 + p] = mI.f[p]; }
            #pragma unroll
            for (int p = 0; p < 4; ++p) { xjv[p] = hJ.f[p]; xjv[4 + p] = mJ.f[p]; }
            U8 ti, tj;
            #pragma unroll
            for (int p = 0; p < 4; ++p) {
                ti.u[p] = pk_rne(__logf(xiv[2*p] + EPSF), __logf(xiv[2*p+1] + EPSF));
                tj.u[p] = pk_rne(__logf(xjv[2*p] + EPSF), __logf(xjv[2*p+1] + EPSF));
            }
            aLi = ti.v; aLj = tj.v;
        }
        // -lxj: bf16 sign flip on the A side (replaces a WLn weight set)
        U8 nj; nj.v = aLj;
        #pragma unroll
        for (int p = 0; p < 4; ++p) nj.u[p] ^= 0x80008000u;

        U8 R, Rl, Aa, Dd;
        #pragma unroll
        for (int p = 0; p < 4; ++p) {
            float a0 = xiv[2*p], a1 = xiv[2*p+1];
            float c0 = xjv[2*p], c1 = xjv[2*p+1];
            float r0 = a0 * __builtin_amdgcn_rcpf(c0 + EPSF);
            float r1 = a1 * __builtin_amdgcn_rcpf(c1 + EPSF);
            float d0 = fabsf(a0 - c0), d1 = fabsf(a1 - c1);
            float g0 = d0 * __builtin_amdgcn_rcpf(fmaxf(a0, c0) + EPSF);
            float g1 = d1 * __builtin_amdgcn_rcpf(fmaxf(a1, c1) + EPSF);
            R.u[p]  = pk_tr(r0, r1);
            Rl.u[p] = pk_tr(r0 - hi_f32(r0), r1 - hi_f32(r1));
            Aa.u[p] = pk_tr(d0, d1);
            Dd.u[p] = pk_tr(g0, g1);
        }

        // opaque offset: stops LICM hoisting weight ds_reads into registers
        int off = lane;
        asm volatile("" : "+v"(off));
        auto ldfrag = [&](int s, int nt) {
            U8 w; w.q4 = sW[(s * 4 + nt) * 64 + off];
            return w.v;
        };

        f32x4 acc[4];
        #pragma unroll
        for (int nt = 0; nt < 4; ++nt) {
            acc[nt][0] = b1v[nt]; acc[nt][1] = b1v[nt];
            acc[nt][2] = b1v[nt]; acc[nt][3] = b1v[nt];
        }
        #pragma unroll
        for (int nt = 0; nt < 4; ++nt) {
            bf16x8 fW0h = ldfrag(0, nt);
            bf16x8 fW0l = ldfrag(1, nt);
            bf16x8 fWL  = ldfrag(2, nt);
            bf16x8 fWA  = ldfrag(3, nt);
            bf16x8 fWD  = ldfrag(4, nt);
            acc[nt] = __builtin_amdgcn_mfma_f32_16x16x32_bf16(R.v,  fW0h, acc[nt], 0, 0, 0);
            acc[nt] = __builtin_amdgcn_mfma_f32_16x16x32_bf16(Rl.v, fW0h, acc[nt], 0, 0, 0);
            acc[nt] = __builtin_amdgcn_mfma_f32_16x16x32_bf16(R.v,  fW0l, acc[nt], 0, 0, 0);
            acc[nt] = __builtin_amdgcn_mfma_f32_16x16x32_bf16(aLi,  fWL,  acc[nt], 0, 0, 0);
            acc[nt] = __builtin_amdgcn_mfma_f32_16x16x32_bf16(nj.v, fWL,  acc[nt], 0, 0, 0);
            acc[nt] = __builtin_amdgcn_mfma_f32_16x16x32_bf16(Aa.v, fWA,  acc[nt], 0, 0, 0);
            acc[nt] = __builtin_amdgcn_mfma_f32_16x16x32_bf16(Dd.v, fWD,  acc[nt], 0, 0, 0);
        }

        // ---- layer 2 + reduce over the 16-lane row via DPP rotate-adds ----
        float p4[4];
        #pragma unroll
        for (int r = 0; r < 4; ++r) {
            float pp = 0.f;
            #pragma unroll
            for (int nt = 0; nt < 4; ++nt)
                pp = fmaf(fmaxf(acc[nt][r], 0.f), w2v[nt], pp);
            pp = dpp_ror_add<0x121>(pp);   // row_ror:1
            pp = dpp_ror_add<0x122>(pp);   // row_ror:2
            pp = dpp_ror_add<0x124>(pp);   // row_ror:4
            pp = dpp_ror_add<0x128>(pp);   // row_ror:8
            p4[r] = pp;                    // all 16 lanes hold the row sum
        }
        if (c < 4) {
            const int e = (tc << 4) + q * 4 + c;
            if (e < E) {
                float v = (c == 0) ? p4[0] : (c == 1) ? p4[1] : (c == 2) ? p4[2] : p4[3];
                if constexpr (SORTED) {
                    out[pidx[e]] = v + b2s;
                } else {
                    out[e] = v + b2s;
                }
            }
        }
    };

    // ---- depth-2 pipeline: slots A (tile t) and B (tile t+tstep) ----
    Q hA, mA, hJA, mJA;      // slot A
    Q hB, mB, hJB, mJB;      // slot B
    int sC, dC;              // idx for tile t+2*tstep (resident)

    { int s, d; ldidx(t,         s, d); gather(s, d, hA, mA, hJA, mJA); }
    { int s, d; ldidx(t + tstep, s, d); gather(s, d, hB, mB, hJB, mJB); }
    ldidx(t + 2 * tstep, sC, dC);

    for (;;) {
        compute(t, hA, mA, hJA, mJA);
        gather(sC, dC, hA, mA, hJA, mJA);     // tile t+2*tstep into slot A
        ldidx(t + 3 * tstep, sC, dC);
        t += tstep; if (t >= t1) break;

        compute(t, hB, mB, hJB, mJB);
        gather(sC, dC, hB, mB, hJB, mJB);     // tile t+2*tstep into slot B
        ldidx(t + 3 * tstep, sC, dC);
        t += tstep; if (t >= t1) break;
    }
}

extern "C" void kernel_launch(void* const* d_in, const int* in_sizes, int n_in,
                              void* d_out, int out_size, void* d_ws, size_t ws_size,
                              hipStream_t stream)
{
    const float* x   = (const float*)d_in[0];
    const int*   ei  = (const int*)  d_in[1];
    const float* W1  = (const float*)d_in[2];
    const float* b1  = (const float*)d_in[3];
    const float* W2  = (const float*)d_in[4];
    const float* b2  = (const float*)d_in[5];
    float* out = (float*)d_out;

    const int E  = out_size;       // 1,000,000
    const int Nd = in_sizes[0];    // N*D = 3,200,000
    const int N  = Nd / DD;        // 100,000

    // workspace layout: rec | ssrc | sdst | sidx | H | Bk | ebase
    const size_t RB   = (size_t)Nd * 4;              // 12.8 MB
    const int    nblk = (E + SB_EB - 1) / SB_EB;     // 245
    const size_t SORT = (size_t)E * 12 + (size_t)nblk * NBUK * 8 + 64;

    uint4*    rec   = (uint4*)d_ws;
    char*     wb    = (char*)d_ws + RB;
    int*      ssrc  = (int*)wb;
    int*      sdst  = ssrc + E;
    int*      sidx  = sdst + E;
    unsigned* H     = (unsigned*)(sidx + E);
    unsigned* Bk    = H + (size_t)nblk * NBUK;
    unsigned* ebase = Bk + (size_t)nblk * NBUK;

    const bool pack   = ws_size >= RB && (Nd % 8) == 0;
    const bool sorted = pack && ws_size >= RB + SORT && E > 0 && N > 0;

    // bucket = floor(src * 8 / N) via magic-mul: __umulhi(src, M)
    const unsigned M = (unsigned)(((8ull << 32) + (unsigned long long)N - 1)
                                  / (unsigned long long)N);

    if (sorted) {
        const int nchunk = Nd / 8;
        prep_pack<<<(nchunk + 255) / 256, 256, 0, stream>>>(x, rec, nchunk);
        hist8<<<nblk, 256, 0, stream>>>(ei, H, E, M);
        scan8<<<1, 64, 0, stream>>>(H, Bk, ebase, nblk);
        scatter8<<<nblk, 256, 0, stream>>>(ei, Bk, ssrc, sdst, sidx, E, M);
        edge_bias_mfma<1, 1><<<2048, 256, 0, stream>>>(
            x, ssrc, sdst, sidx, ebase, W1, b1, W2, b2, rec, out, E);
    } else if (pack) {
        const int nchunk = Nd / 8;
        prep_pack<<<(nchunk + 255) / 256, 256, 0, stream>>>(x, rec, nchunk);
        edge_bias_mfma<1, 0><<<2048, 256, 0, stream>>>(
            x, ei, ei + E, ei, (const unsigned*)ei, W1, b1, W2, b2, rec, out, E);
    } else {
        edge_bias_mfma<0, 0><<<2048, 256, 0, stream>>>(
            x, ei, ei + E, ei, (const unsigned*)ei, W1, b1, W2, b2, rec, out, E);
    }
}

// Round 9
// 131.726 us; speedup vs baseline: 1.4306x; 1.4306x over previous
//
#include <hip/hip_runtime.h>

// NumericalBiasModule: out[e] = b2 + W2 · relu(W1 · rel(x[src], x[dst]) + b1)
// rel = [ratio | log_ratio | abs_diff | rel_diff], 128 features.
//
// Round-26: CHAMPION RESTORE (r0/r17 structure, 65.9us main / 131.5us total).
// Session verdict after 8 structural experiments (r18-r25): the kernel sits
// at the random-line service wall. Arithmetic: 1M edges x 2 nodes x 128B =
// 256MB of 64B-line random traffic (precision-forced, r16) served at
// 3.9 TB/s = the measured random-line ceiling. Falsified levers:
//  - MLP/pipelining neutral 3x (r8/r17/r21) -> rate-, not latency-bound.
//  - 32-edge tiles worse 3x (r18/r19/r21): more in-flight lines, L2 thrash.
//  - L2-miss traffic reduction irrelevant BOTH directions: r22 (miss flat,
//    dur flat), r25 (miss -25%, dur flat) -> line SERVICE, not line source.
//  - Register-resident weights: compiler scratch-spills 20 bf16x8 (r24).
//  - PACK=0 live logs: +11us critical-path VALU (r23).
//  - Full src-sort (seq one side, ~-18us main) costs ~+18-25us sort+scatter:
//    EV <= 0, not attempted.
//
// MFMA tile (validated r4-r16): 16 edges/wave, mfma_f32_16x16x32_bf16.
// lane = (m=lane&15 edge, q=lane>>4 k-chunk); A-frag[j] = feat[m][q*8+j];
// C/D: col=lane&15 (hid), row=q*4+reg (edge).
//
// Structure (validated r16, 64.7us, VGPR 52-56, absmax 2.0): packed node
// record (xh bf16[8] | xl8 u8[8] mantissa ext | lu8 u8[8] log-quant, 32B per
// 8-dim chunk), 20KB LDS weight image read just-in-time (opaque-offset hack
// blocks LICM), DPP row_ror epilogue, __launch_bounds__(256,4), depth-2
// gather pipeline (neutral but never harmful at 16-edge tiles).

#define DD    32
#define HID   64
#define RELF  128
#define EPSF  1e-8f
#define LXLO  -18.420681f          // log(1e-8)
#define LXSC  13.843137f           // 255 / 18.420681
#define LXIV  0.07223796f          // 18.420681 / 255
#define MSC   3.0517578125e-05f    // 2^-15

typedef short  bf16x8 __attribute__((ext_vector_type(8)));
typedef float  f32x4  __attribute__((ext_vector_type(4)));

union U8 { unsigned u[4]; bf16x8 v; uint4 q4; };
union Q  { uint4 v; unsigned u[4]; float f[4]; };

static __device__ __forceinline__ unsigned pk_tr(float lo, float hi) {
    return __builtin_amdgcn_perm(__builtin_bit_cast(unsigned, hi),
                                 __builtin_bit_cast(unsigned, lo), 0x07060302u);
}
static __device__ __forceinline__ unsigned rne_bits(float f) {
    unsigned u = __builtin_bit_cast(unsigned, f);
    return u + 0x7fffu + ((u >> 16) & 1u);
}
static __device__ __forceinline__ unsigned pk_rne(float lo, float hi) {
    return __builtin_amdgcn_perm(rne_bits(hi), rne_bits(lo), 0x07060302u);
}
static __device__ __forceinline__ float hi_f32(float f) {
    return __builtin_bit_cast(float, __builtin_bit_cast(unsigned, f) & 0xffff0000u);
}
static __device__ __forceinline__ float ubyte(unsigned w, int b) {
    return (float)((w >> (8 * b)) & 0xffu);   // folds to v_cvt_f32_ubyteN
}
static __device__ __forceinline__ unsigned q8(float v) {
    int u = (int)(v + 0.5f);
    return (unsigned)(u > 255 ? 255 : (u < 0 ? 0 : u));
}
// pp += row_ror<N>(pp): within-16-lane rotate-add on the VALU pipe (DPP)
template <int CTRL>
static __device__ __forceinline__ float dpp_ror_add(float pp) {
    int s = __builtin_bit_cast(int, pp);
    int t = __builtin_amdgcn_update_dpp(0, s, CTRL, 0xf, 0xf, true);
    return pp + __builtin_bit_cast(float, t);
}

// ---- prep: one thread per (node, q) 8-dim chunk ----
__global__ __launch_bounds__(256)
void prep_pack(const float* __restrict__ x, uint4* __restrict__ rec, int nchunk)
{
    int i = blockIdx.x * blockDim.x + threadIdx.x;   // chunk = node*4 + q
    if (i >= nchunk) return;
    const float4* xp = (const float4*)(x + (size_t)i * 8);
    float4 v0 = xp[0], v1 = xp[1];
    float xv[8] = {v0.x, v0.y, v0.z, v0.w, v1.x, v1.y, v1.z, v1.w};

    unsigned xh[4];
    #pragma unroll
    for (int p = 0; p < 4; ++p) xh[p] = pk_tr(xv[2*p], xv[2*p+1]);

    unsigned xl[2] = {0u, 0u}, lu[2] = {0u, 0u};
    #pragma unroll
    for (int e = 0; e < 8; ++e) {
        float a  = xv[e];
        float ah = hi_f32(a);
        float f  = 0.f;
        if (ah > 0.f)
            f = (a * __builtin_amdgcn_rcpf(ah) - 1.f) * 32768.f;   // 2^15
        xl[e >> 2] |= q8(f) << (8 * (e & 3));
        float lxe = __logf(a + EPSF);
        lu[e >> 2] |= q8((lxe - LXLO) * LXSC) << (8 * (e & 3));
    }

    uint4 r0; r0.x = xh[0]; r0.y = xh[1]; r0.z = xh[2]; r0.w = xh[3];
    uint4 r1; r1.x = xl[0]; r1.y = xl[1]; r1.z = lu[0]; r1.w = lu[1];
    rec[2 * i]     = r0;
    rec[2 * i + 1] = r1;
}

// PACK=1: packed records (2 lines/edge). PACK=0: raw x + per-edge logf.
template <int PACK>
__global__ __launch_bounds__(256, 4)
void edge_bias_mfma(const float* __restrict__ x,
                    const int*   __restrict__ ei,     // [2, E]
                    const float* __restrict__ W1,     // [64, 128]
                    const float* __restrict__ b1,
                    const float* __restrict__ W2,
                    const float* __restrict__ b2,
                    const uint4* __restrict__ rec,    // [N, 8] packed
                    float* __restrict__ out,
                    int E)
{
    const int lane = threadIdx.x & 63;
    const int wv   = threadIdx.x >> 6;
    const int wave = (blockIdx.x * blockDim.x + threadIdx.x) >> 6;
    const int nwv  = (gridDim.x * blockDim.x) >> 6;
    const int c = lane & 15;      // edge-in-tile (A) / hid-col (C)
    const int q = lane >> 4;      // k-chunk (A,B) / row-quad (C)

    // ---- LDS weight image: 5 sets x 4 nt = 20 frags x 1KB (r11/r12) ----
    // 0: W0h (ratio hi)  1: W0l (ratio lo)  2: WL (log)  3: WA  4: WD
    __shared__ uint4 sW[20 * 64];
    for (int s = wv; s < 5; s += 4) {
        #pragma unroll
        for (int nt = 0; nt < 4; ++nt) {
            const float* wr = W1 + (nt * 16 + c) * RELF + q * 8;
            U8 t;
            if (s == 0) {
                #pragma unroll
                for (int p = 0; p < 4; ++p)
                    t.u[p] = pk_tr(wr[2*p], wr[2*p+1]);
            } else if (s == 1) {
                #pragma unroll
                for (int p = 0; p < 4; ++p) {
                    float w0 = wr[2*p], w1 = wr[2*p+1];
                    t.u[p] = pk_rne(w0 - hi_f32(w0), w1 - hi_f32(w1));
                }
            } else {
                const int base = (s == 2) ? 32 : (s == 3) ? 64 : 96;
                #pragma unroll
                for (int p = 0; p < 4; ++p)
                    t.u[p] = pk_rne(wr[base + 2*p], wr[base + 2*p + 1]);
            }
            sW[(s * 4 + nt) * 64 + lane] = t.q4;
        }
    }
    __syncthreads();

    float b1v[4], w2v[4];
    #pragma unroll
    for (int nt = 0; nt < 4; ++nt) {
        b1v[nt] = b1[nt * 16 + c];
        w2v[nt] = W2[nt * 16 + c];
    }
    const float b2s = b2[0];

    const int ntiles = (E + 15) >> 4;
    int t = wave;
    if (t >= ntiles) return;

    auto ldidx = [&](int tt_, int& s, int& d) {
        if (tt_ >= ntiles) tt_ = t;
        int em = (tt_ << 4) + c; if (em > E - 1) em = E - 1;
        s = ei[em]; d = ei[E + em];
    };
    auto gather = [&](int s, int d, Q& hi_, Q& mi_, Q& hj_, Q& mj_) {
        if constexpr (PACK) {
            const uint4* pi = rec + (size_t)s * 8 + q * 2;
            const uint4* pj = rec + (size_t)d * 8 + q * 2;
            hi_.v = pi[0]; mi_.v = pi[1];
            hj_.v = pj[0]; mj_.v = pj[1];
        } else {
            const uint4* pi = (const uint4*)(x + (size_t)s * DD + q * 8);
            const uint4* pj = (const uint4*)(x + (size_t)d * DD + q * 8);
            hi_.v = pi[0]; mi_.v = pi[1];
            hj_.v = pj[0]; mj_.v = pj[1];
        }
    };
    // decode one packed side -> 8 fp32 x + bf16 log A-frag
    auto decode = [&](const Q& h, const Q& m, float* xv, bf16x8& lfrag) {
        #pragma unroll
        for (int p = 0; p < 4; ++p) {
            float lo = __builtin_bit_cast(float, h.u[p] << 16);
            float hi = __builtin_bit_cast(float, h.u[p] & 0xffff0000u);
            unsigned xb = (p < 2) ? m.u[0] : m.u[1];
            float m0 = ubyte(xb, (2 * p) & 3);
            float m1 = ubyte(xb, (2 * p + 1) & 3);
            xv[2 * p]     = fmaf(lo * MSC, m0, lo);
            xv[2 * p + 1] = fmaf(hi * MSC, m1, hi);
        }
        U8 L;
        #pragma unroll
        for (int p = 0; p < 4; ++p) {
            unsigned lb = (p < 2) ? m.u[2] : m.u[3];
            float l0 = fmaf(ubyte(lb, (2 * p) & 3),     LXIV, LXLO);
            float l1 = fmaf(ubyte(lb, (2 * p + 1) & 3), LXIV, LXLO);
            L.u[p] = pk_tr(l0, l1);   // truncate: lx already quantized at 0.036
        }
        lfrag = L.v;
    };

    auto compute = [&](int tc, const Q& hI, const Q& mI, const Q& hJ, const Q& mJ) {
        float xiv[8], xjv[8];
        bf16x8 aLi, aLj;
        if constexpr (PACK) {
            decode(hI, mI, xiv, aLi);
            decode(hJ, mJ, xjv, aLj);
        } else {
            #pragma unroll
            for (int p = 0; p < 4; ++p) { xiv[p] = hI.f[p]; xiv[4 + p] = mI.f[p]; }
            #pragma unroll
            for (int p = 0; p < 4; ++p) { xjv[p] = hJ.f[p]; xjv[4 + p] = mJ.f[p]; }
            U8 ti, tj;
            #pragma unroll
            for (int p = 0; p < 4; ++p) {
                ti.u[p] = pk_rne(__logf(xiv[2*p] + EPSF), __logf(xiv[2*p+1] + EPSF));
                tj.u[p] = pk_rne(__logf(xjv[2*p] + EPSF), __logf(xjv[2*p+1] + EPSF));
            }
            aLi = ti.v; aLj = tj.v;
        }
        // -lxj: bf16 sign flip on the A side (replaces a WLn weight set)
        U8 nj; nj.v = aLj;
        #pragma unroll
        for (int p = 0; p < 4; ++p) nj.u[p] ^= 0x80008000u;

        U8 R, Rl, Aa, Dd;
        #pragma unroll
        for (int p = 0; p < 4; ++p) {
            float a0 = xiv[2*p], a1 = xiv[2*p+1];
            float c0 = xjv[2*p], c1 = xjv[2*p+1];
            float r0 = a0 * __builtin_amdgcn_rcpf(c0 + EPSF);
            float r1 = a1 * __builtin_amdgcn_rcpf(c1 + EPSF);
            float d0 = fabsf(a0 - c0), d1 = fabsf(a1 - c1);
            float g0 = d0 * __builtin_amdgcn_rcpf(fmaxf(a0, c0) + EPSF);
            float g1 = d1 * __builtin_amdgcn_rcpf(fmaxf(a1, c1) + EPSF);
            R.u[p]  = pk_tr(r0, r1);
            Rl.u[p] = pk_tr(r0 - hi_f32(r0), r1 - hi_f32(r1));
            Aa.u[p] = pk_tr(d0, d1);
            Dd.u[p] = pk_tr(g0, g1);
        }

        // opaque offset: stops LICM hoisting weight ds_reads into registers
        int off = lane;
        asm volatile("" : "+v"(off));
        auto ldfrag = [&](int s, int nt) {
            U8 w; w.q4 = sW[(s * 4 + nt) * 64 + off];
            return w.v;
        };

        f32x4 acc[4];
        #pragma unroll
        for (int nt = 0; nt < 4; ++nt) {
            acc[nt][0] = b1v[nt]; acc[nt][1] = b1v[nt];
            acc[nt][2] = b1v[nt]; acc[nt][3] = b1v[nt];
        }
        #pragma unroll
        for (int nt = 0; nt < 4; ++nt) {
            bf16x8 fW0h = ldfrag(0, nt);
            bf16x8 fW0l = ldfrag(1, nt);
            bf16x8 fWL  = ldfrag(2, nt);
            bf16x8 fWA  = ldfrag(3, nt);
            bf16x8 fWD  = ldfrag(4, nt);
            acc[nt] = __builtin_amdgcn_mfma_f32_16x16x32_bf16(R.v,  fW0h, acc[nt], 0, 0, 0);
            acc[nt] = __builtin_amdgcn_mfma_f32_16x16x32_bf16(Rl.v, fW0h, acc[nt], 0, 0, 0);
            acc[nt] = __builtin_amdgcn_mfma_f32_16x16x32_bf16(R.v,  fW0l, acc[nt], 0, 0, 0);
            acc[nt] = __builtin_amdgcn_mfma_f32_16x16x32_bf16(aLi,  fWL,  acc[nt], 0, 0, 0);
            acc[nt] = __builtin_amdgcn_mfma_f32_16x16x32_bf16(nj.v, fWL,  acc[nt], 0, 0, 0);
            acc[nt] = __builtin_amdgcn_mfma_f32_16x16x32_bf16(Aa.v, fWA,  acc[nt], 0, 0, 0);
            acc[nt] = __builtin_amdgcn_mfma_f32_16x16x32_bf16(Dd.v, fWD,  acc[nt], 0, 0, 0);
        }

        // ---- layer 2 + reduce over the 16-lane row via DPP rotate-adds ----
        float p4[4];
        #pragma unroll
        for (int r = 0; r < 4; ++r) {
            float pp = 0.f;
            #pragma unroll
            for (int nt = 0; nt < 4; ++nt)
                pp = fmaf(fmaxf(acc[nt][r], 0.f), w2v[nt], pp);
            pp = dpp_ror_add<0x121>(pp);   // row_ror:1
            pp = dpp_ror_add<0x122>(pp);   // row_ror:2
            pp = dpp_ror_add<0x124>(pp);   // row_ror:4
            pp = dpp_ror_add<0x128>(pp);   // row_ror:8
            p4[r] = pp;                    // all 16 lanes hold the row sum
        }
        if (c < 4) {
            const int e = (tc << 4) + q * 4 + c;
            if (e < E) {
                float v = (c == 0) ? p4[0] : (c == 1) ? p4[1] : (c == 2) ? p4[2] : p4[3];
                out[e] = v + b2s;
            }
        }
    };

    // ---- depth-2 pipeline: slots A (tile t) and B (tile t+nwv) ----
    Q hA, mA, hJA, mJA;      // slot A
    Q hB, mB, hJB, mJB;      // slot B
    int sC, dC;              // idx for tile t+2*nwv (resident)

    { int s, d; ldidx(t,        s, d); gather(s, d, hA, mA, hJA, mJA); }
    { int s, d; ldidx(t + nwv,  s, d); gather(s, d, hB, mB, hJB, mJB); }
    ldidx(t + 2 * nwv, sC, dC);

    for (;;) {
        compute(t, hA, mA, hJA, mJA);
        gather(sC, dC, hA, mA, hJA, mJA);     // tile t+2*nwv into slot A
        ldidx(t + 3 * nwv, sC, dC);
        t += nwv; if (t >= ntiles) break;

        compute(t, hB, mB, hJB, mJB);
        gather(sC, dC, hB, mB, hJB, mJB);     // tile t+2*nwv into slot B
        ldidx(t + 3 * nwv, sC, dC);
        t += nwv; if (t >= ntiles) break;
    }
}

extern "C" void kernel_launch(void* const* d_in, const int* in_sizes, int n_in,
                              void* d_out, int out_size, void* d_ws, size_t ws_size,
                              hipStream_t stream)
{
    const float* x   = (const float*)d_in[0];
    const int*   ei  = (const int*)  d_in[1];
    const float* W1  = (const float*)d_in[2];
    const float* b1  = (const float*)d_in[3];
    const float* W2  = (const float*)d_in[4];
    const float* b2  = (const float*)d_in[5];
    float* out = (float*)d_out;

    const int E  = out_size;       // 1,000,000
    const int Nd = in_sizes[0];    // N*D = 3,200,000
    uint4* rec = (uint4*)d_ws;     // N * 128 bytes = Nd * 4 bytes

    const bool pack = ws_size >= (size_t)Nd * 4 && (Nd % 8) == 0;
    if (pack) {
        const int nchunk = Nd / 8;
        prep_pack<<<(nchunk + 255) / 256, 256, 0, stream>>>(x, rec, nchunk);
        edge_bias_mfma<1><<<2048, 256, 0, stream>>>(x, ei, W1, b1, W2, b2, rec, out, E);
    } else {
        edge_bias_mfma<0><<<2048, 256, 0, stream>>>(x, ei, W1, b1, W2, b2, rec, out, E);
    }
}